// Round 3
// baseline (114.124 us; speedup 1.0000x reference)
//
#include <hip/hip_runtime.h>
#include <math.h>

#define NCH 384
#define RNK 5
#define NA  32
#define NSTART NCH            // starts are < NCH-NA+1; 384 bins for safety

// ws word layout
#define WS_NUM    0                       // RNK*NCH f32
#define WS_NANW   (WS_NUM + RNK*NCH)      // NCH f32
#define WS_TOT    (WS_NANW + NCH)         // 1 f32
#define WS_HIST   (WS_TOT + 1)            // NSTART u32
#define WS_ZERO_WORDS (WS_HIST + NSTART)  // zero [0, WS_ZERO_WORDS)
#define WS_MIN    (WS_ZERO_WORDS)         // 1 u32 (memset 0xFF)
#define WS_OFF    (WS_MIN + 1)            // NSTART+1 u32
#define WS_CUR    (WS_OFF + NSTART + 1)   // NSTART u32
#define WS_STARTS (WS_CUR + NSTART)       // n u16

#define BPB 4                 // blocks per bucket
#define SLICES (BPB*4)        // wave-slices per bucket

__device__ __forceinline__ bool finitef(float v) {
    return fabsf(v) <= 3.402823466e38f;   // NaN fails, +-inf exceeds
}
__device__ __forceinline__ unsigned fenc(float f) {
    unsigned u = __float_as_uint(f);
    return (u & 0x80000000u) ? ~u : (u | 0x80000000u);
}
__device__ __forceinline__ float fdec(unsigned u) {
    unsigned b = (u & 0x80000000u) ? (u ^ 0x80000000u) : ~u;
    return __uint_as_float(b);
}

// ---- pass 1: starts cache + histogram + total weight + global min(lik) ----
__global__ __launch_bounds__(256) void prep_kernel(
    const int* __restrict__ channels, const float* __restrict__ weights,
    const float* __restrict__ lik_data, int n, int nnz,
    unsigned* __restrict__ ws_u, float* __restrict__ ws_f,
    unsigned short* __restrict__ starts)
{
    const int i = blockIdx.x * 256 + threadIdx.x;
    float w = 0.f;
    if (i < n) {
        const int st = channels[(size_t)i * NA];   // channels[i][0] == start_i
        starts[i] = (unsigned short)st;
        atomicAdd(&ws_u[WS_HIST + st], 1u);
        w = weights[i];
    }
    #pragma unroll
    for (int o = 32; o; o >>= 1) w += __shfl_down(w, o);
    if ((threadIdx.x & 63) == 0) atomicAdd(&ws_f[WS_TOT], w);

    float m = 3.402823466e38f;
    const int stride = gridDim.x * blockDim.x;
    const int gtid = blockIdx.x * 256 + threadIdx.x;
    const int n4 = nnz >> 2;
    const float4* d4 = (const float4*)lik_data;
    for (int j = gtid; j < n4; j += stride) {
        float4 v = d4[j];
        m = fminf(m, fminf(fminf(v.x, v.y), fminf(v.z, v.w)));
    }
    for (int j = (n4 << 2) + gtid; j < nnz; j += stride) m = fminf(m, lik_data[j]);
    #pragma unroll
    for (int o = 32; o; o >>= 1) m = fminf(m, __shfl_down(m, o));
    if ((threadIdx.x & 63) == 0) atomicMin(&ws_u[WS_MIN], fenc(m));
}

// ---- pass 2: exclusive scan of 384-bin histogram (single block) ----
__global__ __launch_bounds__(512) void scan_kernel(unsigned* __restrict__ ws_u)
{
    __shared__ unsigned s[NSTART];
    const int t = threadIdx.x;
    if (t < NSTART) s[t] = ws_u[WS_HIST + t];
    __syncthreads();
    for (int d = 1; d < NSTART; d <<= 1) {
        unsigned v = (t >= d && t < NSTART) ? s[t - d] : 0u;
        __syncthreads();
        if (t < NSTART) s[t] += v;
        __syncthreads();
    }
    if (t < NSTART) {
        unsigned excl = s[t] - ws_u[WS_HIST + t];
        ws_u[WS_OFF + t] = excl;
        ws_u[WS_CUR + t] = excl;
        if (t == NSTART - 1) ws_u[WS_OFF + NSTART] = s[t];
    }
}

// ---- pass 3: counting-sort scatter of spike ids ----
__global__ __launch_bounds__(256) void scatter_kernel(
    const unsigned short* __restrict__ starts, unsigned* __restrict__ cur,
    unsigned* __restrict__ order, int n)
{
    int i = blockIdx.x * 256 + threadIdx.x;
    if (i < n) {
        unsigned pos = atomicAdd(&cur[starts[i]], 1u);
        order[pos] = (unsigned)i;
    }
}

// ---- pass 4: bucketed accumulation, pure register tile, zero LDS ----
// bucket b touches exactly channels [b, b+NA): 5x32 = 160 floats.
// lane owns elements {lane, lane+64} (+ lane+128 for lane<32); element e = r*32+a.
__global__ __launch_bounds__(256) void accum_kernel(
    const float* __restrict__ feats, const float* __restrict__ weights,
    const unsigned* __restrict__ order, const unsigned* __restrict__ off,
    float* __restrict__ ws)
{
    const int b    = blockIdx.x % NSTART;
    const int j    = blockIdx.x / NSTART;
    const int wave = threadIdx.x >> 6;
    const int lane = threadIdx.x & 63;
    const int slice = j * 4 + wave;
    const int lo = (int)off[b], hi = (int)off[b + 1];
    if (lo + slice >= hi) return;

    float acc0 = 0.f, acc1 = 0.f, acc2 = 0.f, nanw = 0.f;
    for (int k = lo + slice; k < hi; k += SLICES) {
        const int spike = (int)order[k];
        const float w = weights[spike];
        const float* f = feats + (size_t)spike * (RNK * NA);
        const float v0 = f[lane];            // elements [0,64)   ranks 0-1
        const float v1 = f[lane + 64];       // elements [64,128) ranks 2-3
        float v2 = 0.f;
        if (lane < 32) v2 = f[lane + 128];   // elements [128,160) rank 4
        const float r0 = __shfl(v0, lane & 31);   // rank-0 value of this column
        if (finitef(r0)) {
            acc0 += w * (finitef(v0) ? v0 : 0.f);
            acc1 += w * (finitef(v1) ? v1 : 0.f);
            if (lane < 32) acc2 += w * (finitef(v2) ? v2 : 0.f);
        } else if (lane < 32) {
            nanw += w;                       // NaN column: count weight once
        }
    }

    const int a = lane & 31;
    if (acc0 != 0.f) atomicAdd(&ws[WS_NUM + (lane >> 5) * NCH + b + a], acc0);
    if (acc1 != 0.f) atomicAdd(&ws[WS_NUM + (2 + (lane >> 5)) * NCH + b + a], acc1);
    if (lane < 32) {
        if (acc2 != 0.f) atomicAdd(&ws[WS_NUM + 4 * NCH + b + lane], acc2);
        if (nanw != 0.f) atomicAdd(&ws[WS_NANW + b + lane], nanw);
    }
}

__global__ void finalize_kernel(const float* __restrict__ ws,
                                float* __restrict__ out) {
    int i = blockIdx.x * blockDim.x + threadIdx.x;
    if (i < RNK * NCH) {
        int c = i % NCH;
        float cnt = ws[WS_TOT] - ws[WS_NANW + c];
        out[i] = ws[WS_NUM + i] / cnt;
    }
}

#define MAX_PER 16
__global__ __launch_bounds__(256) void assign_kernel(
    const int* __restrict__ rows, const float* __restrict__ data,
    const unsigned* __restrict__ ws, float* __restrict__ out, int n, int per)
{
    __shared__ float sd[256 * MAX_PER];
    __shared__ int   sr[256 * MAX_PER];
    const int tid = threadIdx.x;
    const int base = blockIdx.x * 256;
    const float offset = fdec(ws[WS_MIN]) - 1.0f;

    if (per <= MAX_PER) {
        const int lim = min(256, n - base) * per;
        const size_t gbase = (size_t)base * per;
        for (int i = tid; i < lim; i += 256) {
            sd[i] = data[gbase + i];
            sr[i] = rows[gbase + i];
        }
        __syncthreads();
        const int spike = base + tid;
        if (spike >= n) return;
        float best_s = -3.402823466e38f;
        int best_row = 0x7FFFFFFF;
        const int o = tid * per;
        for (int j = 0; j < per; ++j) {
            float s = sd[o + j] - offset;    // same f32 op as reference
            int r = sr[o + j];
            if (s > best_s) { best_s = s; best_row = r; }
            else if (s == best_s && r < best_row) best_row = r;
        }
        out[RNK * NCH + spike] = (float)best_row;
    } else {
        const int spike = base + tid;
        if (spike >= n) return;
        const float* d  = data + (size_t)spike * per;
        const int*   rr = rows + (size_t)spike * per;
        float best_s = -3.402823466e38f;
        int best_row = 0x7FFFFFFF;
        for (int j = 0; j < per; ++j) {
            float s = d[j] - offset;
            int r = rr[j];
            if (s > best_s) { best_s = s; best_row = r; }
            else if (s == best_s && r < best_row) best_row = r;
        }
        out[RNK * NCH + spike] = (float)best_row;
    }
}

// ---- fallback (ws too small): R2-style LDS-atomic accumulation ----
__global__ void fb_init_kernel(unsigned* __restrict__ ws) {
    int i = blockIdx.x * blockDim.x + threadIdx.x;
    if (i < WS_ZERO_WORDS + 1) ws[i] = (i == WS_MIN) ? 0xFFFFFFFFu : 0u;
}
__global__ __launch_bounds__(256) void fb_accum_kernel(
    const float* __restrict__ feats, const int* __restrict__ channels,
    const float* __restrict__ weights, float* __restrict__ ws, int n)
{
    __shared__ float s_num[RNK * NCH];
    __shared__ float s_nanw[NCH];
    __shared__ float s_total;
    const int tid = threadIdx.x;
    for (int i = tid; i < RNK * NCH; i += 256) s_num[i] = 0.f;
    for (int i = tid; i < NCH; i += 256) s_nanw[i] = 0.f;
    if (tid == 0) s_total = 0.f;
    __syncthreads();
    const int total = n * NA;
    const int stride = gridDim.x * blockDim.x;
    float tw = 0.f;
    for (int idx = blockIdx.x * blockDim.x + tid; idx < total; idx += stride) {
        const int spike = idx >> 5, a = idx & (NA - 1);
        const int ch = channels[idx];
        const float w = weights[spike];
        if (a == 0) tw += w;
        const float* f = feats + (size_t)spike * (RNK * NA) + a;
        const float v0 = f[0];
        if (finitef(v0)) {
            atomicAdd(&s_num[ch], w * v0);
            #pragma unroll
            for (int r = 1; r < RNK; ++r) {
                float v = f[r * NA];
                if (!finitef(v)) v = 0.f;
                atomicAdd(&s_num[r * NCH + ch], w * v);
            }
        } else atomicAdd(&s_nanw[ch], w);
    }
    #pragma unroll
    for (int off = 32; off; off >>= 1) tw += __shfl_down(tw, off);
    if ((tid & 63) == 0) atomicAdd(&s_total, tw);
    __syncthreads();
    for (int i = tid; i < RNK * NCH; i += 256)
        if (s_num[i] != 0.f) atomicAdd(&ws[WS_NUM + i], s_num[i]);
    for (int i = tid; i < NCH; i += 256)
        if (s_nanw[i] != 0.f) atomicAdd(&ws[WS_NANW + i], s_nanw[i]);
    if (tid == 0) atomicAdd(&ws[WS_TOT], s_total);
}
__global__ void fb_min_kernel(const float* __restrict__ data, int nnz,
                              unsigned* __restrict__ minw) {
    float m = 3.402823466e38f;
    for (int i = blockIdx.x * blockDim.x + threadIdx.x; i < nnz;
         i += gridDim.x * blockDim.x) m = fminf(m, data[i]);
    #pragma unroll
    for (int off = 32; off; off >>= 1) m = fminf(m, __shfl_down(m, off));
    if ((threadIdx.x & 63) == 0) atomicMin(minw, fenc(m));
}

extern "C" void kernel_launch(void* const* d_in, const int* in_sizes, int n_in,
                              void* d_out, int out_size, void* d_ws, size_t ws_size,
                              hipStream_t stream) {
    const float* feats    = (const float*)d_in[0];
    const int*   channels = (const int*)d_in[1];
    const float* weights  = (const float*)d_in[2];
    const int*   lik_rows = (const int*)d_in[3];
    const float* lik_data = (const float*)d_in[5];

    int n   = in_sizes[2];
    int nnz = in_sizes[3];
    int per = nnz / n;

    float*    out = (float*)d_out;
    unsigned* wsu = (unsigned*)d_ws;
    float*    wsf = (float*)d_ws;

    const size_t ws_starts_words = (size_t)(n + 1) / 2;
    const size_t ws_order = WS_STARTS + ws_starts_words;     // word offset
    const size_t req_bytes = (ws_order + (size_t)n) * 4;

    if (ws_size >= req_bytes) {
        hipMemsetAsync(d_ws, 0, (size_t)WS_ZERO_WORDS * 4, stream);
        hipMemsetAsync((char*)d_ws + (size_t)WS_MIN * 4, 0xFF, 4, stream);
        prep_kernel<<<(n + 255) / 256, 256, 0, stream>>>(
            channels, weights, lik_data, n, nnz, wsu, wsf,
            (unsigned short*)(wsu + WS_STARTS));
        scan_kernel<<<1, 512, 0, stream>>>(wsu);
        scatter_kernel<<<(n + 255) / 256, 256, 0, stream>>>(
            (const unsigned short*)(wsu + WS_STARTS), wsu + WS_CUR,
            wsu + ws_order, n);
        accum_kernel<<<NSTART * BPB, 256, 0, stream>>>(
            feats, weights, wsu + ws_order, wsu + WS_OFF, wsf);
        finalize_kernel<<<(RNK * NCH + 255) / 256, 256, 0, stream>>>(wsf, out);
        assign_kernel<<<(n + 255) / 256, 256, 0, stream>>>(
            lik_rows, lik_data, wsu, out, n, per);
    } else {
        fb_init_kernel<<<(WS_ZERO_WORDS + 256) / 256, 256, 0, stream>>>(wsu);
        fb_accum_kernel<<<1024, 256, 0, stream>>>(feats, channels, weights, wsf, n);
        finalize_kernel<<<(RNK * NCH + 255) / 256, 256, 0, stream>>>(wsf, out);
        fb_min_kernel<<<256, 256, 0, stream>>>(lik_data, nnz, wsu + WS_MIN);
        assign_kernel<<<(n + 255) / 256, 256, 0, stream>>>(
            lik_rows, lik_data, wsu, out, n, per);
    }
}

// Round 4
// 109.150 us; speedup vs baseline: 1.0456x; 1.0456x over previous
//
#include <hip/hip_runtime.h>
#include <math.h>

#define NCH 384
#define RNK 5
#define NA  32
#define NSTART NCH            // starts are < NCH-NA+1; 384 bins for safety

// ws word layout
#define WS_NUM    0                       // RNK*NCH f32
#define WS_NANW   (WS_NUM + RNK*NCH)      // NCH f32
#define WS_TOT    (WS_NANW + NCH)         // 1 f32
#define WS_HIST   (WS_TOT + 1)            // NSTART u32
#define WS_ZERO_WORDS (WS_HIST + NSTART)  // zero [0, WS_ZERO_WORDS)
#define WS_MIN    (WS_ZERO_WORDS)         // 1 u32 (init 0xFFFFFFFF)
#define WS_OFF    (WS_MIN + 1)            // NSTART+1 u32
#define WS_CUR    (WS_OFF + NSTART + 1)   // NSTART u32
#define WS_STARTS (WS_CUR + NSTART)       // n u16

#define BPB 4                 // blocks per bucket
#define SLICES (BPB*4)        // wave-slices per bucket

__device__ __forceinline__ bool finitef(float v) {
    return fabsf(v) <= 3.402823466e38f;   // NaN fails, +-inf exceeds
}
__device__ __forceinline__ unsigned fenc(float f) {
    unsigned u = __float_as_uint(f);
    return (u & 0x80000000u) ? ~u : (u | 0x80000000u);
}
__device__ __forceinline__ float fdec(unsigned u) {
    unsigned b = (u & 0x80000000u) ? (u ^ 0x80000000u) : ~u;
    return __uint_as_float(b);
}

// ---- pass 0: init accumulators (NO hipMemsetAsync: rocclr fill kernels
// cost ~40 us each inside the captured graph) ----
__global__ void init_ws_kernel(unsigned* __restrict__ ws) {
    int i = blockIdx.x * blockDim.x + threadIdx.x;
    if (i < WS_ZERO_WORDS) ws[i] = 0u;
    if (i == 0) ws[WS_MIN] = 0xFFFFFFFFu;
}

// ---- pass 1: starts cache + histogram + total weight + global min(lik) ----
__global__ __launch_bounds__(256) void prep_kernel(
    const int* __restrict__ channels, const float* __restrict__ weights,
    const float* __restrict__ lik_data, int n, int nnz,
    unsigned* __restrict__ ws_u, float* __restrict__ ws_f,
    unsigned short* __restrict__ starts)
{
    const int i = blockIdx.x * 256 + threadIdx.x;
    float w = 0.f;
    if (i < n) {
        const int st = channels[(size_t)i * NA];   // channels[i][0] == start_i
        starts[i] = (unsigned short)st;
        atomicAdd(&ws_u[WS_HIST + st], 1u);
        w = weights[i];
    }
    #pragma unroll
    for (int o = 32; o; o >>= 1) w += __shfl_down(w, o);
    if ((threadIdx.x & 63) == 0) atomicAdd(&ws_f[WS_TOT], w);

    float m = 3.402823466e38f;
    const int stride = gridDim.x * blockDim.x;
    const int gtid = blockIdx.x * 256 + threadIdx.x;
    const int n4 = nnz >> 2;
    const float4* d4 = (const float4*)lik_data;
    for (int j = gtid; j < n4; j += stride) {
        float4 v = d4[j];
        m = fminf(m, fminf(fminf(v.x, v.y), fminf(v.z, v.w)));
    }
    for (int j = (n4 << 2) + gtid; j < nnz; j += stride) m = fminf(m, lik_data[j]);
    #pragma unroll
    for (int o = 32; o; o >>= 1) m = fminf(m, __shfl_down(m, o));
    if ((threadIdx.x & 63) == 0) atomicMin(&ws_u[WS_MIN], fenc(m));
}

// ---- pass 2: exclusive scan of 384-bin histogram (single block) ----
__global__ __launch_bounds__(512) void scan_kernel(unsigned* __restrict__ ws_u)
{
    __shared__ unsigned s[NSTART];
    const int t = threadIdx.x;
    if (t < NSTART) s[t] = ws_u[WS_HIST + t];
    __syncthreads();
    for (int d = 1; d < NSTART; d <<= 1) {
        unsigned v = (t >= d && t < NSTART) ? s[t - d] : 0u;
        __syncthreads();
        if (t < NSTART) s[t] += v;
        __syncthreads();
    }
    if (t < NSTART) {
        unsigned excl = s[t] - ws_u[WS_HIST + t];
        ws_u[WS_OFF + t] = excl;
        ws_u[WS_CUR + t] = excl;
        if (t == NSTART - 1) ws_u[WS_OFF + NSTART] = s[t];
    }
}

// ---- pass 3: counting-sort scatter of spike ids ----
__global__ __launch_bounds__(256) void scatter_kernel(
    const unsigned short* __restrict__ starts, unsigned* __restrict__ cur,
    unsigned* __restrict__ order, int n)
{
    int i = blockIdx.x * 256 + threadIdx.x;
    if (i < n) {
        unsigned pos = atomicAdd(&cur[starts[i]], 1u);
        order[pos] = (unsigned)i;
    }
}

// ---- pass 4: bucketed accumulation, pure register tile, zero LDS ----
// bucket b touches exactly channels [b, b+NA): 5x32 = 160 floats.
// lane owns elements {lane, lane+64} (+ lane+128 for lane<32); element e = r*32+a.
__global__ __launch_bounds__(256) void accum_kernel(
    const float* __restrict__ feats, const float* __restrict__ weights,
    const unsigned* __restrict__ order, const unsigned* __restrict__ off,
    float* __restrict__ ws)
{
    const int b    = blockIdx.x % NSTART;
    const int j    = blockIdx.x / NSTART;
    const int wave = threadIdx.x >> 6;
    const int lane = threadIdx.x & 63;
    const int slice = j * 4 + wave;
    const int lo = (int)off[b], hi = (int)off[b + 1];
    if (lo + slice >= hi) return;

    float acc0 = 0.f, acc1 = 0.f, acc2 = 0.f, nanw = 0.f;
    for (int k = lo + slice; k < hi; k += SLICES) {
        const int spike = (int)order[k];
        const float w = weights[spike];
        const float* f = feats + (size_t)spike * (RNK * NA);
        const float v0 = f[lane];            // elements [0,64)   ranks 0-1
        const float v1 = f[lane + 64];       // elements [64,128) ranks 2-3
        float v2 = 0.f;
        if (lane < 32) v2 = f[lane + 128];   // elements [128,160) rank 4
        const float r0 = __shfl(v0, lane & 31);   // rank-0 value of this column
        if (finitef(r0)) {
            acc0 += w * (finitef(v0) ? v0 : 0.f);
            acc1 += w * (finitef(v1) ? v1 : 0.f);
            if (lane < 32) acc2 += w * (finitef(v2) ? v2 : 0.f);
        } else if (lane < 32) {
            nanw += w;                       // NaN column: count weight once
        }
    }

    const int a = lane & 31;
    if (acc0 != 0.f) atomicAdd(&ws[WS_NUM + (lane >> 5) * NCH + b + a], acc0);
    if (acc1 != 0.f) atomicAdd(&ws[WS_NUM + (2 + (lane >> 5)) * NCH + b + a], acc1);
    if (lane < 32) {
        if (acc2 != 0.f) atomicAdd(&ws[WS_NUM + 4 * NCH + b + lane], acc2);
        if (nanw != 0.f) atomicAdd(&ws[WS_NANW + b + lane], nanw);
    }
}

__global__ void finalize_kernel(const float* __restrict__ ws,
                                float* __restrict__ out) {
    int i = blockIdx.x * blockDim.x + threadIdx.x;
    if (i < RNK * NCH) {
        int c = i % NCH;
        float cnt = ws[WS_TOT] - ws[WS_NANW + c];
        out[i] = ws[WS_NUM + i] / cnt;
    }
}

#define MAX_PER 16
__global__ __launch_bounds__(256) void assign_kernel(
    const int* __restrict__ rows, const float* __restrict__ data,
    const unsigned* __restrict__ ws, float* __restrict__ out, int n, int per)
{
    __shared__ float sd[256 * MAX_PER];
    __shared__ int   sr[256 * MAX_PER];
    const int tid = threadIdx.x;
    const int base = blockIdx.x * 256;
    const float offset = fdec(ws[WS_MIN]) - 1.0f;

    if (per <= MAX_PER) {
        const int lim = min(256, n - base) * per;
        const size_t gbase = (size_t)base * per;
        for (int i = tid; i < lim; i += 256) {
            sd[i] = data[gbase + i];
            sr[i] = rows[gbase + i];
        }
        __syncthreads();
        const int spike = base + tid;
        if (spike >= n) return;
        float best_s = -3.402823466e38f;
        int best_row = 0x7FFFFFFF;
        const int o = tid * per;
        for (int j = 0; j < per; ++j) {
            float s = sd[o + j] - offset;    // same f32 op as reference
            int r = sr[o + j];
            if (s > best_s) { best_s = s; best_row = r; }
            else if (s == best_s && r < best_row) best_row = r;
        }
        out[RNK * NCH + spike] = (float)best_row;
    } else {
        const int spike = base + tid;
        if (spike >= n) return;
        const float* d  = data + (size_t)spike * per;
        const int*   rr = rows + (size_t)spike * per;
        float best_s = -3.402823466e38f;
        int best_row = 0x7FFFFFFF;
        for (int j = 0; j < per; ++j) {
            float s = d[j] - offset;
            int r = rr[j];
            if (s > best_s) { best_s = s; best_row = r; }
            else if (s == best_s && r < best_row) best_row = r;
        }
        out[RNK * NCH + spike] = (float)best_row;
    }
}

// ---- fallback (ws too small): R2-style LDS-atomic accumulation ----
__global__ void fb_init_kernel(unsigned* __restrict__ ws) {
    int i = blockIdx.x * blockDim.x + threadIdx.x;
    if (i < WS_ZERO_WORDS + 1) ws[i] = (i == WS_MIN) ? 0xFFFFFFFFu : 0u;
}
__global__ __launch_bounds__(256) void fb_accum_kernel(
    const float* __restrict__ feats, const int* __restrict__ channels,
    const float* __restrict__ weights, float* __restrict__ ws, int n)
{
    __shared__ float s_num[RNK * NCH];
    __shared__ float s_nanw[NCH];
    __shared__ float s_total;
    const int tid = threadIdx.x;
    for (int i = tid; i < RNK * NCH; i += 256) s_num[i] = 0.f;
    for (int i = tid; i < NCH; i += 256) s_nanw[i] = 0.f;
    if (tid == 0) s_total = 0.f;
    __syncthreads();
    const int total = n * NA;
    const int stride = gridDim.x * blockDim.x;
    float tw = 0.f;
    for (int idx = blockIdx.x * blockDim.x + tid; idx < total; idx += stride) {
        const int spike = idx >> 5, a = idx & (NA - 1);
        const int ch = channels[idx];
        const float w = weights[spike];
        if (a == 0) tw += w;
        const float* f = feats + (size_t)spike * (RNK * NA) + a;
        const float v0 = f[0];
        if (finitef(v0)) {
            atomicAdd(&s_num[ch], w * v0);
            #pragma unroll
            for (int r = 1; r < RNK; ++r) {
                float v = f[r * NA];
                if (!finitef(v)) v = 0.f;
                atomicAdd(&s_num[r * NCH + ch], w * v);
            }
        } else atomicAdd(&s_nanw[ch], w);
    }
    #pragma unroll
    for (int off = 32; off; off >>= 1) tw += __shfl_down(tw, off);
    if ((tid & 63) == 0) atomicAdd(&s_total, tw);
    __syncthreads();
    for (int i = tid; i < RNK * NCH; i += 256)
        if (s_num[i] != 0.f) atomicAdd(&ws[WS_NUM + i], s_num[i]);
    for (int i = tid; i < NCH; i += 256)
        if (s_nanw[i] != 0.f) atomicAdd(&ws[WS_NANW + i], s_nanw[i]);
    if (tid == 0) atomicAdd(&ws[WS_TOT], s_total);
}
__global__ void fb_min_kernel(const float* __restrict__ data, int nnz,
                              unsigned* __restrict__ minw) {
    float m = 3.402823466e38f;
    for (int i = blockIdx.x * blockDim.x + threadIdx.x; i < nnz;
         i += gridDim.x * blockDim.x) m = fminf(m, data[i]);
    #pragma unroll
    for (int off = 32; off; off >>= 1) m = fminf(m, __shfl_down(m, off));
    if ((threadIdx.x & 63) == 0) atomicMin(minw, fenc(m));
}

extern "C" void kernel_launch(void* const* d_in, const int* in_sizes, int n_in,
                              void* d_out, int out_size, void* d_ws, size_t ws_size,
                              hipStream_t stream) {
    const float* feats    = (const float*)d_in[0];
    const int*   channels = (const int*)d_in[1];
    const float* weights  = (const float*)d_in[2];
    const int*   lik_rows = (const int*)d_in[3];
    const float* lik_data = (const float*)d_in[5];

    int n   = in_sizes[2];
    int nnz = in_sizes[3];
    int per = nnz / n;

    float*    out = (float*)d_out;
    unsigned* wsu = (unsigned*)d_ws;
    float*    wsf = (float*)d_ws;

    const size_t ws_starts_words = (size_t)(n + 1) / 2;
    const size_t ws_order = WS_STARTS + ws_starts_words;     // word offset
    const size_t req_bytes = (ws_order + (size_t)n) * 4;

    if (ws_size >= req_bytes) {
        init_ws_kernel<<<(WS_ZERO_WORDS + 255) / 256, 256, 0, stream>>>(wsu);
        prep_kernel<<<(n + 255) / 256, 256, 0, stream>>>(
            channels, weights, lik_data, n, nnz, wsu, wsf,
            (unsigned short*)(wsu + WS_STARTS));
        scan_kernel<<<1, 512, 0, stream>>>(wsu);
        scatter_kernel<<<(n + 255) / 256, 256, 0, stream>>>(
            (const unsigned short*)(wsu + WS_STARTS), wsu + WS_CUR,
            wsu + ws_order, n);
        accum_kernel<<<NSTART * BPB, 256, 0, stream>>>(
            feats, weights, wsu + ws_order, wsu + WS_OFF, wsf);
        finalize_kernel<<<(RNK * NCH + 255) / 256, 256, 0, stream>>>(wsf, out);
        assign_kernel<<<(n + 255) / 256, 256, 0, stream>>>(
            lik_rows, lik_data, wsu, out, n, per);
    } else {
        fb_init_kernel<<<(WS_ZERO_WORDS + 256) / 256, 256, 0, stream>>>(wsu);
        fb_accum_kernel<<<1024, 256, 0, stream>>>(feats, channels, weights, wsf, n);
        finalize_kernel<<<(RNK * NCH + 255) / 256, 256, 0, stream>>>(wsf, out);
        fb_min_kernel<<<256, 256, 0, stream>>>(lik_data, nnz, wsu + WS_MIN);
        assign_kernel<<<(n + 255) / 256, 256, 0, stream>>>(
            lik_rows, lik_data, wsu, out, n, per);
    }
}